// Round 11
// baseline (2342.878 us; speedup 1.0000x reference)
//
#include <hip/hip_runtime.h>

#define HEADS 16
#define DIM_HEAD 64
#define T_SEQ 16
#define D_MODEL 1024
#define MAX_REL 16

typedef _Float16 half8 __attribute__((ext_vector_type(8)));
typedef float f32x4 __attribute__((ext_vector_type(4)));

// ---------------------------------------------------------------------------
// fp32 -> fp16 conversion, 8 elems/thread
// ---------------------------------------------------------------------------
__global__ __launch_bounds__(256)
void cvt_f32_f16(const float* __restrict__ in, _Float16* __restrict__ out, int n8) {
  int i = blockIdx.x * blockDim.x + threadIdx.x;
  if (i >= n8) return;
  float4 a = ((const float4*)in)[2 * i];
  float4 b = ((const float4*)in)[2 * i + 1];
  half8 h;
  h[0] = (_Float16)a.x; h[1] = (_Float16)a.y;
  h[2] = (_Float16)a.z; h[3] = (_Float16)a.w;
  h[4] = (_Float16)b.x; h[5] = (_Float16)b.y;
  h[6] = (_Float16)b.z; h[7] = (_Float16)b.w;
  ((half8*)out)[i] = h;
}

// ---------------------------------------------------------------------------
// One-shot rel-table prep: RKh[32][64] fp16 (row-major), RVth[64][32] fp16
// ---------------------------------------------------------------------------
__global__ __launch_bounds__(256)
void prep_tables(const float* __restrict__ relk, const float* __restrict__ relv,
                 _Float16* __restrict__ RKh, _Float16* __restrict__ RVth) {
  const int i = threadIdx.x;
  {
    int m = i >> 3, d0 = (i & 7) * 8;
    float4 a = *(const float4*)(relk + m * 64 + d0);
    float4 b = *(const float4*)(relk + m * 64 + d0 + 4);
    half8 h;
    h[0] = (_Float16)a.x; h[1] = (_Float16)a.y;
    h[2] = (_Float16)a.z; h[3] = (_Float16)a.w;
    h[4] = (_Float16)b.x; h[5] = (_Float16)b.y;
    h[6] = (_Float16)b.z; h[7] = (_Float16)b.w;
    *(half8*)(RKh + m * 64 + d0) = h;
  }
  {
    int d = i >> 2, m0 = (i & 3) * 8;
    half8 h;
#pragma unroll
    for (int e = 0; e < 8; ++e) h[e] = (_Float16)relv[(m0 + e) * 64 + d];
    *(half8*)(RVth + d * 32 + m0) = h;
  }
}

// ---------------------------------------------------------------------------
// async global -> LDS, 16B per lane (dest = wave-uniform base + lane*16)
// ---------------------------------------------------------------------------
__device__ __forceinline__ void gload_lds16(const _Float16* g, _Float16* l) {
  __builtin_amdgcn_global_load_lds(
      (const __attribute__((address_space(1))) unsigned int*)(uintptr_t)g,
      (__attribute__((address_space(3))) unsigned int*)(uintptr_t)l, 16, 0, 0);
}

// ---------------------------------------------------------------------------
// 256x256 MFMA fp16 GEMM, BK=32, 8 waves (2M x 4N), TWO blocks/CU.
// C[M,N] = A[M,K]*B[N,K]^T.
// LDS [buf][A/B][128][64] fp16 = 64 KB total -> 2 blocks/CU: when this
// block's waves sit at a barrier/drain, the co-resident block's waves issue
// MFMA (cross-block overlap, the m97 mechanism). Layout packs 2 operand rows
// (32 fp16 = 64B each) per 128B LDS row; XOR swizzle on 16B slots
// (phys = log ^ (ldsrow&7)) keeps frag reads 2-way (free).
// Phase skeleton per K-tile (R8-proven): 2 phases x {ds_read, stage,
// lgkmcnt(0)+sched_barrier, setprio, 16 MFMA, barrier}; vmcnt(0) at tile end.
// ---------------------------------------------------------------------------
template <bool OUT_F16>
__global__ __launch_bounds__(512, 4)
void gemm256(const _Float16* __restrict__ A, const _Float16* __restrict__ B,
             const float* __restrict__ bias, void* __restrict__ Cv,
             int M, int N, int K) {
  __shared__ _Float16 lds[2][2][128][64];
  const int tid = threadIdx.x;
  const int wave = tid >> 6, lane = tid & 63;
  const int wm = wave >> 2, wn = wave & 3;

  // XCD-aware bijective remap (m204)
  const int GN = N >> 8;
  const int nwg = gridDim.x;
  const int q = nwg >> 3, r = nwg & 7;
  const int xcd = blockIdx.x & 7, pos = blockIdx.x >> 3;
  const int wgid = (xcd < r ? xcd * (q + 1) : r * (q + 1) + (xcd - r) * q) + pos;
  const int bm = wgid / GN, bn = wgid % GN;

  const int fr = lane & 15;          // frag row/col within 16
  const int q4 = lane >> 4;          // 0..3 : 16B k-slot within 32-elem row
  const int l3 = lane >> 3;          // LDS row within 8-row group
  const int sl = (lane & 7) ^ l3;    // logical slot this lane must fetch

  const _Float16* Ag = A + (size_t)(bm * 256) * K;
  const _Float16* Bg = B + (size_t)(bn * 256) * K;

  f32x4 acc[8][4];
#pragma unroll
  for (int m = 0; m < 8; ++m)
#pragma unroll
    for (int n = 0; n < 4; ++n) acc[m][n] = (f32x4){0.f, 0.f, 0.f, 0.f};

  // stage group g (0..15): operand rows 16g..16g+15 -> LDS rows 8g..8g+7.
  // LDS row holds operand rows {2r, 2r+1}: logical slot s<4 -> row 2r k-slot s,
  // s>=4 -> row 2r+1 k-slot s-4. Dest linear; source pre-swizzled.
  auto stage_group = [&](int buf, int ab, int g, const _Float16* G, int k0) {
    const _Float16* src =
        G + (size_t)(g * 16 + 2 * l3 + (sl >> 2)) * K + k0 + (sl & 3) * 8;
    gload_lds16(src, &lds[buf][ab][g * 8][0]);
  };

  auto ldOp = [&](int buf, int ab, int R) {  // R = operand row 0..255
    int lrow = R >> 1;
    unsigned logs = (unsigned)((R & 1) * 4 + q4);
    unsigned off = (unsigned)(lrow * 128) + ((logs ^ (unsigned)(lrow & 7)) * 16);
    return *(const half8*)((const char*)&lds[buf][ab][0][0] + off);
  };

  half8 bF[4];
  auto mm = [&](int mb, half8 (&af)[4]) {
    __builtin_amdgcn_s_setprio(1);
#pragma unroll
    for (int i = 0; i < 4; ++i)
#pragma unroll
      for (int nf = 0; nf < 4; ++nf)
        acc[mb + i][nf] = __builtin_amdgcn_mfma_f32_16x16x32_f16(
            af[i], bF[nf], acc[mb + i][nf], 0, 0, 0);
    __builtin_amdgcn_s_setprio(0);
  };

  // prologue: stage tile 0 fully (2 A-groups + 2 B-groups per wave)
  stage_group(0, 0, wave * 2 + 0, Ag, 0);
  stage_group(0, 0, wave * 2 + 1, Ag, 0);
  stage_group(0, 1, wave * 2 + 0, Bg, 0);
  stage_group(0, 1, wave * 2 + 1, Bg, 0);
  asm volatile("s_waitcnt vmcnt(0)" ::: "memory");
  __builtin_amdgcn_s_barrier();

  const int NT = K >> 5;
  for (int t = 0; t < NT; ++t) {
    const int cur = t & 1, nxt = cur ^ 1;
    const bool pf = (t + 1 < NT);
    const int k1 = (t + 1) << 5;
    half8 aF[4];

    // ---- p0: read B + A mf0-3; stage A-groups of t+1 ----
#pragma unroll
    for (int nf = 0; nf < 4; ++nf) bF[nf] = ldOp(cur, 1, wn * 64 + nf * 16 + fr);
#pragma unroll
    for (int i = 0; i < 4; ++i) aF[i] = ldOp(cur, 0, wm * 128 + i * 16 + fr);
    if (pf) {
      stage_group(nxt, 0, wave * 2 + 0, Ag, k1);
      stage_group(nxt, 0, wave * 2 + 1, Ag, k1);
    }
    asm volatile("s_waitcnt lgkmcnt(0)" ::: "memory");
    __builtin_amdgcn_sched_barrier(0);
    mm(0, aF);
    __builtin_amdgcn_sched_barrier(0);
    __builtin_amdgcn_s_barrier();

    // ---- p1: read A mf4-7; stage B-groups of t+1; tile-end drain ----
#pragma unroll
    for (int i = 0; i < 4; ++i)
      aF[i] = ldOp(cur, 0, wm * 128 + (i + 4) * 16 + fr);
    if (pf) {
      stage_group(nxt, 1, wave * 2 + 0, Bg, k1);
      stage_group(nxt, 1, wave * 2 + 1, Bg, k1);
    }
    asm volatile("s_waitcnt lgkmcnt(0)" ::: "memory");
    __builtin_amdgcn_sched_barrier(0);
    mm(4, aF);
    __builtin_amdgcn_sched_barrier(0);
    if (pf) asm volatile("s_waitcnt vmcnt(0)" ::: "memory");
    __builtin_amdgcn_s_barrier();
  }

  // ---- epilogue ----
  const int row_l = q4 * 4;
#pragma unroll
  for (int mf = 0; mf < 8; ++mf) {
#pragma unroll
    for (int nf = 0; nf < 4; ++nf) {
      int col = bn * 256 + wn * 64 + nf * 16 + fr;
#pragma unroll
      for (int r4 = 0; r4 < 4; ++r4) {
        int row = bm * 256 + wm * 128 + mf * 16 + row_l + r4;
        if (OUT_F16) {
          ((_Float16*)Cv)[(size_t)row * N + col] = (_Float16)acc[mf][nf][r4];
        } else {
          ((float*)Cv)[(size_t)row * N + col] = acc[mf][nf][r4] + bias[col];
        }
      }
    }
  }
}

// ---------------------------------------------------------------------------
// MFMA attention: one wave per head, 4 heads per block. Rel-table MFMA
// B-frags read directly from precomputed fp16 tables in global (L2-hot).
// All LDS is wave-private -> no __syncthreads at all.
// ---------------------------------------------------------------------------
__global__ __launch_bounds__(256)
void attn_mfma(const _Float16* __restrict__ QKV,
               const _Float16* __restrict__ RKh, const _Float16* __restrict__ RVth,
               _Float16* __restrict__ O) {
  __shared__ _Float16 PB[4][16][72];     // [P(0:16) | zero(16:32) | B2(32:64)]
  __shared__ _Float16 VtP[4][64][40];    // [V^T(0:16) | zero(16:32)]

  const int tid = threadIdx.x;
  const int wave = tid >> 6, lane = tid & 63;

#pragma unroll
  for (int z = 0; z < 6; ++z) {
    int idx = z * 64 + lane;
    int row = idx / 24, cd = idx % 24;
    *(unsigned int*)&PB[wave][row][16 + 2 * cd] = 0u;
  }
#pragma unroll
  for (int z = 0; z < 8; ++z) {
    int idx = z * 64 + lane;
    int row = idx >> 3, cd = idx & 7;
    *(unsigned int*)&VtP[wave][row][16 + 2 * cd] = 0u;
  }

  const int bh = blockIdx.x * 4 + wave;
  const int b = bh >> 4, h = bh & 15;
  const size_t qbase = (size_t)(b * T_SEQ) * 3072 + h * 64;
  const int fr = lane & 15, fk8 = (lane >> 4) * 8;

  half8 aQ0 = *(const half8*)(QKV + qbase + (size_t)fr * 3072 + fk8);
  half8 aQ1 = *(const half8*)(QKV + qbase + (size_t)fr * 3072 + 32 + fk8);
  half8 bK0 = *(const half8*)(QKV + qbase + 1024 + (size_t)fr * 3072 + fk8);
  half8 bK1 = *(const half8*)(QKV + qbase + 1024 + (size_t)fr * 3072 + 32 + fk8);

  half8 rk0a = *(const half8*)(RKh + fr * 64 + fk8);
  half8 rk0b = *(const half8*)(RKh + fr * 64 + 32 + fk8);
  half8 rk1a = *(const half8*)(RKh + (16 + fr) * 64 + fk8);
  half8 rk1b = *(const half8*)(RKh + (16 + fr) * 64 + 32 + fk8);

  {
    const _Float16* vp = QKV + qbase + 2048 + (size_t)fr * 3072 + (lane >> 4) * 16;
    half8 v0 = *(const half8*)vp;
    half8 v1 = *(const half8*)(vp + 8);
    int d0 = (lane >> 4) * 16;
#pragma unroll
    for (int e = 0; e < 8; ++e) VtP[wave][d0 + e][fr] = v0[e];
#pragma unroll
    for (int e = 0; e < 8; ++e) VtP[wave][d0 + 8 + e][fr] = v1[e];
  }

  f32x4 accS = {0.f, 0.f, 0.f, 0.f};
  accS = __builtin_amdgcn_mfma_f32_16x16x32_f16(aQ0, bK0, accS, 0, 0, 0);
  accS = __builtin_amdgcn_mfma_f32_16x16x32_f16(aQ1, bK1, accS, 0, 0, 0);

  f32x4 G0 = {0.f, 0.f, 0.f, 0.f}, G1 = {0.f, 0.f, 0.f, 0.f};
  G0 = __builtin_amdgcn_mfma_f32_16x16x32_f16(aQ0, rk0a, G0, 0, 0, 0);
  G0 = __builtin_amdgcn_mfma_f32_16x16x32_f16(aQ1, rk0b, G0, 0, 0, 0);
  G1 = __builtin_amdgcn_mfma_f32_16x16x32_f16(aQ0, rk1a, G1, 0, 0, 0);
  G1 = __builtin_amdgcn_mfma_f32_16x16x32_f16(aQ1, rk1b, G1, 0, 0, 0);

  const int ibase = (lane >> 4) * 4;
#pragma unroll
  for (int r = 0; r < 4; ++r) {
    const int i = ibase + r;
    const int ridx = fr - i + MAX_REL;
    const int src = (lane & 48) | (ridx & 15);
    float g0 = __shfl(G0[r], src);
    float g1 = __shfl(G1[r], src);
    float g = (ridx >= 16) ? g1 : g0;
    float s = (accS[r] + g) * 0.125f;
    float mx = s;
#pragma unroll
    for (int w = 8; w >= 1; w >>= 1) mx = fmaxf(mx, __shfl_xor(mx, w));
    float e = __expf(s - mx);
    float sum = e;
#pragma unroll
    for (int w = 8; w >= 1; w >>= 1) sum += __shfl_xor(sum, w);
    _Float16 ph = (_Float16)(e / sum);
    PB[wave][i][fr] = ph;
    PB[wave][i][32 + (fr - i + MAX_REL)] = ph;
  }

  half8 aP0 = *(const half8*)&PB[wave][fr][fk8];
  half8 aP1 = *(const half8*)&PB[wave][fr][32 + fk8];
  const size_t obase = (size_t)(b * T_SEQ) * D_MODEL + h * 64;
#pragma unroll
  for (int t = 0; t < 4; ++t) {
    half8 bv = *(const half8*)&VtP[wave][t * 16 + fr][fk8];
    half8 br = *(const half8*)(RVth + (t * 16 + fr) * 32 + fk8);
    f32x4 o = {0.f, 0.f, 0.f, 0.f};
    o = __builtin_amdgcn_mfma_f32_16x16x32_f16(aP0, bv, o, 0, 0, 0);
    o = __builtin_amdgcn_mfma_f32_16x16x32_f16(aP1, br, o, 0, 0, 0);
#pragma unroll
    for (int r = 0; r < 4; ++r)
      O[obase + (size_t)(ibase + r) * D_MODEL + t * 16 + fr] = (_Float16)o[r];
  }
}

// ---------------------------------------------------------------------------
extern "C" void kernel_launch(void* const* d_in, const int* in_sizes, int n_in,
                              void* d_out, int out_size, void* d_ws, size_t ws_size,
                              hipStream_t stream) {
  const float* x  = (const float*)d_in[0];
  const float* Wq = (const float*)d_in[1];
  const float* Wk = (const float*)d_in[2];
  const float* Wv = (const float*)d_in[3];
  const float* Wo = (const float*)d_in[4];
  const float* bo = (const float*)d_in[5];
  const float* rk = (const float*)d_in[6];
  const float* rv = (const float*)d_in[7];
  float* out = (float*)d_out;

  const int total_rows = 2048 * T_SEQ;           // 32768
  const size_t wsz = (size_t)D_MODEL * D_MODEL;  // 1M elems per weight

  _Float16* Wqkvh = (_Float16*)d_ws;
  _Float16* Woh  = Wqkvh + 3 * wsz;
  _Float16* RKh  = Woh + wsz;            // 32*64 = 2048
  _Float16* RVth = RKh + 2048;           // 64*32 = 2048
  _Float16* chunk_base = RVth + 2048;

  {
    int n8 = (int)(wsz / 8);
    int blocks = (n8 + 255) / 256;
    cvt_f32_f16<<<blocks, 256, 0, stream>>>(Wq, Wqkvh, n8);
    cvt_f32_f16<<<blocks, 256, 0, stream>>>(Wk, Wqkvh + wsz, n8);
    cvt_f32_f16<<<blocks, 256, 0, stream>>>(Wv, Wqkvh + 2 * wsz, n8);
    cvt_f32_f16<<<blocks, 256, 0, stream>>>(Wo, Woh, n8);
    prep_tables<<<1, 256, 0, stream>>>(rk, rv, RKh, RVth);
  }

  // per-chunk: xh (1024) + QKV (3072) + AO (1024) fp16 per row
  const size_t per_row_bytes = (size_t)5120 * sizeof(_Float16);
  size_t avail = ws_size - (size_t)(4 * wsz + 4096) * sizeof(_Float16);
  size_t rows_fit = avail / per_row_bytes;
  int rows_c = (rows_fit > (size_t)total_rows) ? total_rows : (int)rows_fit;
  rows_c = (rows_c / 256) * 256;
  if (rows_c < 256) rows_c = 256;

  for (int r0 = 0; r0 < total_rows; r0 += rows_c) {
    int rc = total_rows - r0;
    if (rc > rows_c) rc = rows_c;

    _Float16* xh   = chunk_base;
    _Float16* QKVb = xh + (size_t)rows_c * 1024;
    _Float16* AO   = QKVb + (size_t)rows_c * 3072;

    {
      int n8 = rc * 128;
      cvt_f32_f16<<<(n8 + 255) / 256, 256, 0, stream>>>(
          x + (size_t)r0 * D_MODEL, xh, n8);
    }

    gemm256<true><<<(3072 / 256) * (rc / 256), 512, 0, stream>>>(
        xh, Wqkvh, nullptr, QKVb, rc, 3072, 1024);

    attn_mfma<<<rc / 4, 256, 0, stream>>>(QKVb, RKh, RVth, AO);

    gemm256<false><<<(1024 / 256) * (rc / 256), 512, 0, stream>>>(
        AO, Woh, bo, out + (size_t)r0 * D_MODEL, rc, 1024, 1024);
  }
}

// Round 12
// 499.759 us; speedup vs baseline: 4.6880x; 4.6880x over previous
//
#include <hip/hip_runtime.h>

#define HEADS 16
#define DIM_HEAD 64
#define T_SEQ 16
#define D_MODEL 1024
#define MAX_REL 16

typedef _Float16 half8 __attribute__((ext_vector_type(8)));
typedef float f32x4 __attribute__((ext_vector_type(4)));

// ---------------------------------------------------------------------------
// fp32 -> fp16 conversion, 8 elems/thread (weights only now)
// ---------------------------------------------------------------------------
__global__ __launch_bounds__(256)
void cvt_f32_f16(const float* __restrict__ in, _Float16* __restrict__ out, int n8) {
  int i = blockIdx.x * blockDim.x + threadIdx.x;
  if (i >= n8) return;
  float4 a = ((const float4*)in)[2 * i];
  float4 b = ((const float4*)in)[2 * i + 1];
  half8 h;
  h[0] = (_Float16)a.x; h[1] = (_Float16)a.y;
  h[2] = (_Float16)a.z; h[3] = (_Float16)a.w;
  h[4] = (_Float16)b.x; h[5] = (_Float16)b.y;
  h[6] = (_Float16)b.z; h[7] = (_Float16)b.w;
  ((half8*)out)[i] = h;
}

// ---------------------------------------------------------------------------
// One-shot rel-table prep: RKh[32][64] fp16 (row-major), RVth[64][32] fp16
// ---------------------------------------------------------------------------
__global__ __launch_bounds__(256)
void prep_tables(const float* __restrict__ relk, const float* __restrict__ relv,
                 _Float16* __restrict__ RKh, _Float16* __restrict__ RVth) {
  const int i = threadIdx.x;
  {
    int m = i >> 3, d0 = (i & 7) * 8;
    float4 a = *(const float4*)(relk + m * 64 + d0);
    float4 b = *(const float4*)(relk + m * 64 + d0 + 4);
    half8 h;
    h[0] = (_Float16)a.x; h[1] = (_Float16)a.y;
    h[2] = (_Float16)a.z; h[3] = (_Float16)a.w;
    h[4] = (_Float16)b.x; h[5] = (_Float16)b.y;
    h[6] = (_Float16)b.z; h[7] = (_Float16)b.w;
    *(half8*)(RKh + m * 64 + d0) = h;
  }
  {
    int d = i >> 2, m0 = (i & 3) * 8;
    half8 h;
#pragma unroll
    for (int e = 0; e < 8; ++e) h[e] = (_Float16)relv[(m0 + e) * 64 + d];
    *(half8*)(RVth + d * 32 + m0) = h;
  }
}

// ---------------------------------------------------------------------------
// async global -> LDS, 16B per lane (dest = wave-uniform base + lane*16)
// ---------------------------------------------------------------------------
__device__ __forceinline__ void gload_lds16(const _Float16* g, _Float16* l) {
  __builtin_amdgcn_global_load_lds(
      (const __attribute__((address_space(1))) unsigned int*)(uintptr_t)g,
      (__attribute__((address_space(3))) unsigned int*)(uintptr_t)l, 16, 0, 0);
}

// ---------------------------------------------------------------------------
// 256x256 MFMA fp16 GEMM, BK=64, 8 waves (2M x 4N). R8-proven phase skeleton
// (no leading barrier; lgkmcnt(0)+sched_barrier fence; setprio; end barrier;
// p3 vmcnt(0)). LDS [buf][A/B][half][128][64] fp16 = 128 KB, XOR-swizzled
// 16B slots (slot ^= row&7).
// A_F32: A read as fp32, converted in-register, ds_write'd into the SAME
// swizzled LDS image (T14 split: loads for tile t+2 issued at p1, written at
// p0/p1 of tile t+1, drained by p3 vmcnt(0) => 2-phase cover). B always
// staged via global_load_lds with pre-swizzled source.
// ---------------------------------------------------------------------------
template <bool OUT_F16, bool A_F32>
__global__ __launch_bounds__(512, 2)
void gemm256(const void* __restrict__ Av, const _Float16* __restrict__ B,
             const float* __restrict__ bias, void* __restrict__ Cv,
             int M, int N, int K) {
  __shared__ _Float16 lds[2][2][2][128][64];
  const int tid = threadIdx.x;
  const int wave = tid >> 6, lane = tid & 63;
  const int wm = wave >> 2, wn = wave & 3;

  // XCD-aware bijective remap (m204)
  const int GN = N >> 8;
  const int nwg = gridDim.x;
  const int q = nwg >> 3, r = nwg & 7;
  const int xcd = blockIdx.x & 7, pos = blockIdx.x >> 3;
  const int wgid = (xcd < r ? xcd * (q + 1) : r * (q + 1) + (xcd - r) * q) + pos;
  const int bm = wgid / GN, bn = wgid % GN;

  const int fr = lane & 15;          // frag row/col within 16
  const int q4 = lane >> 4;          // 0..3 : 16B slot within 64B k-half
  const int l3 = lane >> 3;          // staging row within 8-row group
  const int sl = (lane & 7) ^ l3;    // pre-swizzled source slot

  const _Float16* Ag16 = (const _Float16*)Av + (size_t)(bm * 256) * K;
  const float*    Ag32 = (const float*)Av + (size_t)(bm * 256) * K;
  const _Float16* Bg = B + (size_t)(bn * 256) * K;

  f32x4 acc[8][4];
#pragma unroll
  for (int m = 0; m < 8; ++m)
#pragma unroll
    for (int n = 0; n < 4; ++n) acc[m][n] = (f32x4){0.f, 0.f, 0.f, 0.f};

  // gload staging of one 128x64 half-tile (2 x gload_lds per thread)
  auto stage_half = [&](int buf, int ab, int half, const _Float16* G, int k0) {
#pragma unroll
    for (int i = 0; i < 2; ++i) {
      int g = wave * 2 + i;  // 8-row group 0..15
      const _Float16* src =
          G + (size_t)(half * 128 + g * 8 + l3) * K + k0 + sl * 8;
      gload_lds16(src, &lds[buf][ab][half][g * 8][0]);
    }
  };

  // reg-staged A (fp32 source): load raw fp32 (no wait at issue)
  f32x4 pend[2][2][2];  // [half][group][lo/hi] -- all indices compile-time
  auto ldA32 = [&](f32x4 (&dst)[2][2][2], int k0) {
#pragma unroll
    for (int h = 0; h < 2; ++h)
#pragma unroll
      for (int i = 0; i < 2; ++i) {
        const float* s =
            Ag32 + (size_t)(h * 128 + (wave * 2 + i) * 8 + l3) * K + k0 + sl * 8;
        dst[h][i][0] = *(const f32x4*)s;
        dst[h][i][1] = *(const f32x4*)(s + 4);
      }
  };
  // cvt + ds_write one half, reproducing gload's exact LDS image
  auto writeAhalf = [&](int buf, int h, f32x4 (&src)[2][2][2]) {
#pragma unroll
    for (int i = 0; i < 2; ++i) {
      half8 v;
#pragma unroll
      for (int e = 0; e < 4; ++e) {
        v[e] = (_Float16)src[h][i][0][e];
        v[4 + e] = (_Float16)src[h][i][1][e];
      }
      *(half8*)((char*)&lds[buf][0][h][(wave * 2 + i) * 8][0] + lane * 16) = v;
    }
  };

  auto ldA = [&](int buf, int mf, int ks) {
    unsigned off = (unsigned)((mf * 16 + fr) * 128 + (ks * 4 + q4) * 16) ^
                   (unsigned)((fr & 7) << 4);
    return *(const half8*)((const char*)&lds[buf][0][wm][0][0] + off);
  };
  auto ldB = [&](int buf, int nf, int ks) {
    int rowB = wn * 64 + nf * 16 + fr;
    unsigned off = (unsigned)((rowB & 127) * 128 + (ks * 4 + q4) * 16) ^
                   (unsigned)((fr & 7) << 4);
    return *(const half8*)((const char*)&lds[buf][1][rowB >> 7][0][0] + off);
  };

  half8 bF[4][2];
  auto mm = [&](int p, half8 (&af)[2][2]) {
    __builtin_amdgcn_s_setprio(1);
#pragma unroll
    for (int i = 0; i < 2; ++i)
#pragma unroll
      for (int nf = 0; nf < 4; ++nf)
#pragma unroll
        for (int ks = 0; ks < 2; ++ks)
          acc[p * 2 + i][nf] = __builtin_amdgcn_mfma_f32_16x16x32_f16(
              af[i][ks], bF[nf][ks], acc[p * 2 + i][nf], 0, 0, 0);
    __builtin_amdgcn_s_setprio(0);
  };

  const int NT = K >> 6;

  // ---- prologue: tile 0 into buf0; A of tile 1 into pend regs ----
  if constexpr (A_F32) {
    f32x4 t0[2][2][2];
    ldA32(t0, 0);                          // 4 float4 loads
    stage_half(0, 1, 0, Bg, 0);            // 4 B gloads
    stage_half(0, 1, 1, Bg, 0);
    writeAhalf(0, 0, t0);                  // compiler waits t0 loads
    writeAhalf(0, 1, t0);
    if (NT > 1) {
      ldA32(pend, 64);                     // tile1 A in flight
      asm volatile("s_waitcnt vmcnt(4)" ::: "memory");  // B landed; pend out
    } else {
      asm volatile("s_waitcnt vmcnt(0)" ::: "memory");
    }
    asm volatile("s_waitcnt lgkmcnt(0)" ::: "memory");
  } else {
    stage_half(0, 0, 0, Ag16, 0);
    stage_half(0, 0, 1, Ag16, 0);
    stage_half(0, 1, 0, Bg, 0);
    stage_half(0, 1, 1, Bg, 0);
    asm volatile("s_waitcnt vmcnt(0)" ::: "memory");
  }
  __builtin_amdgcn_s_barrier();

  for (int t = 0; t < NT; ++t) {
    const int cur = t & 1, nxt = cur ^ 1;
    const bool pf = (t + 1 < NT);
    const bool pf2 = (t + 2 < NT);
    const int k1 = (t + 1) << 6;
    half8 aF[2][2];

    // ---- p0: read B + A-q0; stage A-half0 of t+1 ----
#pragma unroll
    for (int nf = 0; nf < 4; ++nf)
#pragma unroll
      for (int ks = 0; ks < 2; ++ks) bF[nf][ks] = ldB(cur, nf, ks);
#pragma unroll
    for (int i = 0; i < 2; ++i)
#pragma unroll
      for (int ks = 0; ks < 2; ++ks) aF[i][ks] = ldA(cur, i, ks);
    if (pf) {
      if constexpr (A_F32) writeAhalf(nxt, 0, pend);
      else stage_half(nxt, 0, 0, Ag16, k1);
    }
    asm volatile("s_waitcnt lgkmcnt(0)" ::: "memory");
    __builtin_amdgcn_sched_barrier(0);
    mm(0, aF);
    __builtin_amdgcn_sched_barrier(0);
    __builtin_amdgcn_s_barrier();

    // ---- p1: read A-q1; stage A-half1; issue A-loads for t+2 ----
#pragma unroll
    for (int i = 0; i < 2; ++i)
#pragma unroll
      for (int ks = 0; ks < 2; ++ks) aF[i][ks] = ldA(cur, 2 + i, ks);
    if (pf) {
      if constexpr (A_F32) {
        writeAhalf(nxt, 1, pend);
        if (pf2) ldA32(pend, (t + 2) << 6);
      } else {
        stage_half(nxt, 0, 1, Ag16, k1);
      }
    }
    asm volatile("s_waitcnt lgkmcnt(0)" ::: "memory");
    __builtin_amdgcn_sched_barrier(0);
    mm(1, aF);
    __builtin_amdgcn_sched_barrier(0);
    __builtin_amdgcn_s_barrier();

    // ---- p2: read A-q2; stage B-half0 ----
#pragma unroll
    for (int i = 0; i < 2; ++i)
#pragma unroll
      for (int ks = 0; ks < 2; ++ks) aF[i][ks] = ldA(cur, 4 + i, ks);
    if (pf) stage_half(nxt, 1, 0, Bg, k1);
    asm volatile("s_waitcnt lgkmcnt(0)" ::: "memory");
    __builtin_amdgcn_sched_barrier(0);
    mm(2, aF);
    __builtin_amdgcn_sched_barrier(0);
    __builtin_amdgcn_s_barrier();

    // ---- p3: read A-q3; stage B-half1; tile-boundary drain ----
#pragma unroll
    for (int i = 0; i < 2; ++i)
#pragma unroll
      for (int ks = 0; ks < 2; ++ks) aF[i][ks] = ldA(cur, 6 + i, ks);
    if (pf) stage_half(nxt, 1, 1, Bg, k1);
    asm volatile("s_waitcnt lgkmcnt(0)" ::: "memory");
    __builtin_amdgcn_sched_barrier(0);
    mm(3, aF);
    __builtin_amdgcn_sched_barrier(0);
    if (pf) asm volatile("s_waitcnt vmcnt(0)" ::: "memory");
    __builtin_amdgcn_s_barrier();
  }

  // ---- epilogue ----
  const int row_l = q4 * 4;
#pragma unroll
  for (int mf = 0; mf < 8; ++mf) {
#pragma unroll
    for (int nf = 0; nf < 4; ++nf) {
      int col = bn * 256 + wn * 64 + nf * 16 + fr;
#pragma unroll
      for (int r4 = 0; r4 < 4; ++r4) {
        int row = bm * 256 + wm * 128 + mf * 16 + row_l + r4;
        if (OUT_F16) {
          ((_Float16*)Cv)[(size_t)row * N + col] = (_Float16)acc[mf][nf][r4];
        } else {
          ((float*)Cv)[(size_t)row * N + col] = acc[mf][nf][r4] + bias[col];
        }
      }
    }
  }
}

// ---------------------------------------------------------------------------
// MFMA attention: one wave per head, 4 heads per block. Rel-table MFMA
// B-frags read directly from precomputed fp16 tables in global (L2-hot).
// All LDS is wave-private -> no __syncthreads at all.
// ---------------------------------------------------------------------------
__global__ __launch_bounds__(256)
void attn_mfma(const _Float16* __restrict__ QKV,
               const _Float16* __restrict__ RKh, const _Float16* __restrict__ RVth,
               _Float16* __restrict__ O) {
  __shared__ _Float16 PB[4][16][72];     // [P(0:16) | zero(16:32) | B2(32:64)]
  __shared__ _Float16 VtP[4][64][40];    // [V^T(0:16) | zero(16:32)]

  const int tid = threadIdx.x;
  const int wave = tid >> 6, lane = tid & 63;

#pragma unroll
  for (int z = 0; z < 6; ++z) {
    int idx = z * 64 + lane;
    int row = idx / 24, cd = idx % 24;
    *(unsigned int*)&PB[wave][row][16 + 2 * cd] = 0u;
  }
#pragma unroll
  for (int z = 0; z < 8; ++z) {
    int idx = z * 64 + lane;
    int row = idx >> 3, cd = idx & 7;
    *(unsigned int*)&VtP[wave][row][16 + 2 * cd] = 0u;
  }

  const int bh = blockIdx.x * 4 + wave;
  const int b = bh >> 4, h = bh & 15;
  const size_t qbase = (size_t)(b * T_SEQ) * 3072 + h * 64;
  const int fr = lane & 15, fk8 = (lane >> 4) * 8;

  half8 aQ0 = *(const half8*)(QKV + qbase + (size_t)fr * 3072 + fk8);
  half8 aQ1 = *(const half8*)(QKV + qbase + (size_t)fr * 3072 + 32 + fk8);
  half8 bK0 = *(const half8*)(QKV + qbase + 1024 + (size_t)fr * 3072 + fk8);
  half8 bK1 = *(const half8*)(QKV + qbase + 1024 + (size_t)fr * 3072 + 32 + fk8);

  half8 rk0a = *(const half8*)(RKh + fr * 64 + fk8);
  half8 rk0b = *(const half8*)(RKh + fr * 64 + 32 + fk8);
  half8 rk1a = *(const half8*)(RKh + (16 + fr) * 64 + fk8);
  half8 rk1b = *(const half8*)(RKh + (16 + fr) * 64 + 32 + fk8);

  {
    const _Float16* vp = QKV + qbase + 2048 + (size_t)fr * 3072 + (lane >> 4) * 16;
    half8 v0 = *(const half8*)vp;
    half8 v1 = *(const half8*)(vp + 8);
    int d0 = (lane >> 4) * 16;
#pragma unroll
    for (int e = 0; e < 8; ++e) VtP[wave][d0 + e][fr] = v0[e];
#pragma unroll
    for (int e = 0; e < 8; ++e) VtP[wave][d0 + 8 + e][fr] = v1[e];
  }

  f32x4 accS = {0.f, 0.f, 0.f, 0.f};
  accS = __builtin_amdgcn_mfma_f32_16x16x32_f16(aQ0, bK0, accS, 0, 0, 0);
  accS = __builtin_amdgcn_mfma_f32_16x16x32_f16(aQ1, bK1, accS, 0, 0, 0);

  f32x4 G0 = {0.f, 0.f, 0.f, 0.f}, G1 = {0.f, 0.f, 0.f, 0.f};
  G0 = __builtin_amdgcn_mfma_f32_16x16x32_f16(aQ0, rk0a, G0, 0, 0, 0);
  G0 = __builtin_amdgcn_mfma_f32_16x16x32_f16(aQ1, rk0b, G0, 0, 0, 0);
  G1 = __builtin_amdgcn_mfma_f32_16x16x32_f16(aQ0, rk1a, G1, 0, 0, 0);
  G1 = __builtin_amdgcn_mfma_f32_16x16x32_f16(aQ1, rk1b, G1, 0, 0, 0);

  const int ibase = (lane >> 4) * 4;
#pragma unroll
  for (int r = 0; r < 4; ++r) {
    const int i = ibase + r;
    const int ridx = fr - i + MAX_REL;
    const int src = (lane & 48) | (ridx & 15);
    float g0 = __shfl(G0[r], src);
    float g1 = __shfl(G1[r], src);
    float g = (ridx >= 16) ? g1 : g0;
    float s = (accS[r] + g) * 0.125f;
    float mx = s;
#pragma unroll
    for (int w = 8; w >= 1; w >>= 1) mx = fmaxf(mx, __shfl_xor(mx, w));
    float e = __expf(s - mx);
    float sum = e;
#pragma unroll
    for (int w = 8; w >= 1; w >>= 1) sum += __shfl_xor(sum, w);
    _Float16 ph = (_Float16)(e / sum);
    PB[wave][i][fr] = ph;
    PB[wave][i][32 + (fr - i + MAX_REL)] = ph;
  }

  half8 aP0 = *(const half8*)&PB[wave][fr][fk8];
  half8 aP1 = *(const half8*)&PB[wave][fr][32 + fk8];
  const size_t obase = (size_t)(b * T_SEQ) * D_MODEL + h * 64;
#pragma unroll
  for (int t = 0; t < 4; ++t) {
    half8 bv = *(const half8*)&VtP[wave][t * 16 + fr][fk8];
    half8 br = *(const half8*)(RVth + (t * 16 + fr) * 32 + fk8);
    f32x4 o = {0.f, 0.f, 0.f, 0.f};
    o = __builtin_amdgcn_mfma_f32_16x16x32_f16(aP0, bv, o, 0, 0, 0);
    o = __builtin_amdgcn_mfma_f32_16x16x32_f16(aP1, br, o, 0, 0, 0);
#pragma unroll
    for (int r = 0; r < 4; ++r)
      O[obase + (size_t)(ibase + r) * D_MODEL + t * 16 + fr] = (_Float16)o[r];
  }
}

// ---------------------------------------------------------------------------
extern "C" void kernel_launch(void* const* d_in, const int* in_sizes, int n_in,
                              void* d_out, int out_size, void* d_ws, size_t ws_size,
                              hipStream_t stream) {
  const float* x  = (const float*)d_in[0];
  const float* Wq = (const float*)d_in[1];
  const float* Wk = (const float*)d_in[2];
  const float* Wv = (const float*)d_in[3];
  const float* Wo = (const float*)d_in[4];
  const float* bo = (const float*)d_in[5];
  const float* rk = (const float*)d_in[6];
  const float* rv = (const float*)d_in[7];
  float* out = (float*)d_out;

  const int total_rows = 2048 * T_SEQ;           // 32768
  const size_t wsz = (size_t)D_MODEL * D_MODEL;  // 1M elems per weight

  _Float16* Wqkvh = (_Float16*)d_ws;
  _Float16* Woh  = Wqkvh + 3 * wsz;
  _Float16* RKh  = Woh + wsz;            // 32*64 = 2048
  _Float16* RVth = RKh + 2048;           // 64*32 = 2048
  _Float16* chunk_base = RVth + 2048;

  {
    int n8 = (int)(wsz / 8);
    int blocks = (n8 + 255) / 256;
    cvt_f32_f16<<<blocks, 256, 0, stream>>>(Wq, Wqkvh, n8);
    cvt_f32_f16<<<blocks, 256, 0, stream>>>(Wk, Wqkvh + wsz, n8);
    cvt_f32_f16<<<blocks, 256, 0, stream>>>(Wv, Wqkvh + 2 * wsz, n8);
    cvt_f32_f16<<<blocks, 256, 0, stream>>>(Wo, Woh, n8);
    prep_tables<<<1, 256, 0, stream>>>(rk, rv, RKh, RVth);
  }

  // per-chunk: QKV (3072) + AO (1024) fp16 per row (x read directly as fp32)
  const size_t per_row_bytes = (size_t)4096 * sizeof(_Float16);
  size_t avail = ws_size - (size_t)(4 * wsz + 4096) * sizeof(_Float16);
  size_t rows_fit = avail / per_row_bytes;
  int rows_c = (rows_fit > (size_t)total_rows) ? total_rows : (int)rows_fit;
  rows_c = (rows_c / 256) * 256;
  if (rows_c < 256) rows_c = 256;

  for (int r0 = 0; r0 < total_rows; r0 += rows_c) {
    int rc = total_rows - r0;
    if (rc > rows_c) rc = rows_c;

    _Float16* QKVb = chunk_base;
    _Float16* AO   = QKVb + (size_t)rows_c * 3072;

    gemm256<true, true><<<(3072 / 256) * (rc / 256), 512, 0, stream>>>(
        x + (size_t)r0 * D_MODEL, Wqkvh, nullptr, QKVb, rc, 3072, 1024);

    attn_mfma<<<rc / 4, 256, 0, stream>>>(QKVb, RKh, RVth, AO);

    gemm256<false, false><<<(1024 / 256) * (rc / 256), 512, 0, stream>>>(
        AO, Woh, bo, out + (size_t)r0 * D_MODEL, rc, 1024, 1024);
  }
}

// Round 13
// 410.326 us; speedup vs baseline: 5.7098x; 1.2180x over previous
//
#include <hip/hip_runtime.h>

#define HEADS 16
#define DIM_HEAD 64
#define T_SEQ 16
#define D_MODEL 1024
#define MAX_REL 16

typedef _Float16 half8 __attribute__((ext_vector_type(8)));
typedef float f32x4 __attribute__((ext_vector_type(4)));

// ---------------------------------------------------------------------------
// fp32 -> fp16 conversion, 8 elems/thread (x only)
// ---------------------------------------------------------------------------
__global__ __launch_bounds__(256)
void cvt_f32_f16(const float* __restrict__ in, _Float16* __restrict__ out, int n8) {
  int i = blockIdx.x * blockDim.x + threadIdx.x;
  if (i >= n8) return;
  float4 a = ((const float4*)in)[2 * i];
  float4 b = ((const float4*)in)[2 * i + 1];
  half8 h;
  h[0] = (_Float16)a.x; h[1] = (_Float16)a.y;
  h[2] = (_Float16)a.z; h[3] = (_Float16)a.w;
  h[4] = (_Float16)b.x; h[5] = (_Float16)b.y;
  h[6] = (_Float16)b.z; h[7] = (_Float16)b.w;
  ((half8*)out)[i] = h;
}

// ---------------------------------------------------------------------------
// Single prologue kernel: converts all 4 weights (blocks 0..2047, 512 per
// weight) and preps rel tables (block 2048).
// Wdst layout: [Wq; Wk; Wv; Wo] contiguous fp16 (4M elems).
// RKh[32][64] fp16 row-major; RVth[64][32] fp16 = relv transposed.
// ---------------------------------------------------------------------------
__global__ __launch_bounds__(256)
void prep_all(const float* __restrict__ Wq, const float* __restrict__ Wk,
              const float* __restrict__ Wv, const float* __restrict__ Wo,
              _Float16* __restrict__ Wdst,
              const float* __restrict__ relk, const float* __restrict__ relv,
              _Float16* __restrict__ RKh, _Float16* __restrict__ RVth) {
  const int bid = blockIdx.x;
  if (bid < 2048) {
    const int w = bid >> 9;  // 0..3
    const float* src = (w == 0) ? Wq : (w == 1) ? Wk : (w == 2) ? Wv : Wo;
    const int local = (bid & 511) * 256 + threadIdx.x;  // half8 index, 0..131071
    float4 a = ((const float4*)src)[2 * local];
    float4 b = ((const float4*)src)[2 * local + 1];
    half8 h;
    h[0] = (_Float16)a.x; h[1] = (_Float16)a.y;
    h[2] = (_Float16)a.z; h[3] = (_Float16)a.w;
    h[4] = (_Float16)b.x; h[5] = (_Float16)b.y;
    h[6] = (_Float16)b.z; h[7] = (_Float16)b.w;
    ((half8*)Wdst)[(size_t)w * 131072 + local] = h;
  } else {
    const int i = threadIdx.x;
    {
      int m = i >> 3, d0 = (i & 7) * 8;
      float4 a = *(const float4*)(relk + m * 64 + d0);
      float4 b = *(const float4*)(relk + m * 64 + d0 + 4);
      half8 h;
      h[0] = (_Float16)a.x; h[1] = (_Float16)a.y;
      h[2] = (_Float16)a.z; h[3] = (_Float16)a.w;
      h[4] = (_Float16)b.x; h[5] = (_Float16)b.y;
      h[6] = (_Float16)b.z; h[7] = (_Float16)b.w;
      *(half8*)(RKh + m * 64 + d0) = h;
    }
    {
      int d = i >> 2, m0 = (i & 3) * 8;
      half8 h;
#pragma unroll
      for (int e = 0; e < 8; ++e) h[e] = (_Float16)relv[(m0 + e) * 64 + d];
      *(half8*)(RVth + d * 32 + m0) = h;
    }
  }
}

// ---------------------------------------------------------------------------
// async global -> LDS, 16B per lane (dest = wave-uniform base + lane*16)
// ---------------------------------------------------------------------------
__device__ __forceinline__ void gload_lds16(const _Float16* g, _Float16* l) {
  __builtin_amdgcn_global_load_lds(
      (const __attribute__((address_space(1))) unsigned int*)(uintptr_t)g,
      (__attribute__((address_space(3))) unsigned int*)(uintptr_t)l, 16, 0, 0);
}

// ---------------------------------------------------------------------------
// 256x256 MFMA fp16 GEMM, BK=64, 8 waves (2M x 4N), phase-split pipeline.
// C[M,N] = A[M,K]*B[N,K]^T. LDS [buf][A/B][half][128][64] fp16 = 128 KB,
// XOR-swizzled 16B slots (slot ^= row&7), staged via global_load_lds with
// pre-swizzled global source. R8-proven skeleton: no leading barrier
// (cross-wave read||MFMA overlap), lgkmcnt(0)+sched_barrier fence, setprio
// around MFMA cluster, p3 vmcnt(0) gating buffer swap, end-of-phase barrier.
// ---------------------------------------------------------------------------
template <bool OUT_F16>
__global__ __launch_bounds__(512, 2)
void gemm256(const _Float16* __restrict__ A, const _Float16* __restrict__ B,
             const float* __restrict__ bias, void* __restrict__ Cv,
             int M, int N, int K) {
  __shared__ _Float16 lds[2][2][2][128][64];
  const int tid = threadIdx.x;
  const int wave = tid >> 6, lane = tid & 63;
  const int wm = wave >> 2, wn = wave & 3;

  // XCD-aware bijective remap (m204)
  const int GN = N >> 8;
  const int nwg = gridDim.x;
  const int q = nwg >> 3, r = nwg & 7;
  const int xcd = blockIdx.x & 7, pos = blockIdx.x >> 3;
  const int wgid = (xcd < r ? xcd * (q + 1) : r * (q + 1) + (xcd - r) * q) + pos;
  const int bm = wgid / GN, bn = wgid % GN;

  const int fr = lane & 15;          // frag row/col within 16
  const int q4 = lane >> 4;          // 0..3 : 16B slot within 64B k-half
  const int l3 = lane >> 3;          // staging row within 8-row group
  const int sl = (lane & 7) ^ l3;    // pre-swizzled source slot

  const _Float16* Ag = A + (size_t)(bm * 256) * K;
  const _Float16* Bg = B + (size_t)(bn * 256) * K;

  f32x4 acc[8][4];
#pragma unroll
  for (int m = 0; m < 8; ++m)
#pragma unroll
    for (int n = 0; n < 4; ++n) acc[m][n] = (f32x4){0.f, 0.f, 0.f, 0.f};

  // stage one 128x64 half-tile (2 x gload_lds per thread)
  auto stage_half = [&](int buf, int ab, int half, const _Float16* G, int k0) {
#pragma unroll
    for (int i = 0; i < 2; ++i) {
      int g = wave * 2 + i;  // 8-row group 0..15
      const _Float16* src =
          G + (size_t)(half * 128 + g * 8 + l3) * K + k0 + sl * 8;
      gload_lds16(src, &lds[buf][ab][half][g * 8][0]);
    }
  };

  auto ldA = [&](int buf, int mf, int ks) {
    unsigned off = (unsigned)((mf * 16 + fr) * 128 + (ks * 4 + q4) * 16) ^
                   (unsigned)((fr & 7) << 4);
    return *(const half8*)((const char*)&lds[buf][0][wm][0][0] + off);
  };
  auto ldB = [&](int buf, int nf, int ks) {
    int rowB = wn * 64 + nf * 16 + fr;
    unsigned off = (unsigned)((rowB & 127) * 128 + (ks * 4 + q4) * 16) ^
                   (unsigned)((fr & 7) << 4);
    return *(const half8*)((const char*)&lds[buf][1][rowB >> 7][0][0] + off);
  };

  // prologue: stage tile 0 fully
#pragma unroll
  for (int h = 0; h < 2; ++h) {
    stage_half(0, 0, h, Ag, 0);
    stage_half(0, 1, h, Bg, 0);
  }
  asm volatile("s_waitcnt vmcnt(0)" ::: "memory");
  __builtin_amdgcn_s_barrier();

  const int NT = K >> 6;
  for (int t = 0; t < NT; ++t) {
    const int cur = t & 1, nxt = cur ^ 1;
    const bool pf = (t + 1 < NT);
    const int k1 = (t + 1) << 6;
    half8 bF[4][2];
#pragma unroll
    for (int p = 0; p < 4; ++p) {
      // ---- ds_reads for this phase's quadrant + 1 half-tile stage ----
      half8 aF[2][2];
#pragma unroll
      for (int i = 0; i < 2; ++i)
#pragma unroll
        for (int ks = 0; ks < 2; ++ks) aF[i][ks] = ldA(cur, p * 2 + i, ks);
      if (p == 0) {
#pragma unroll
        for (int nf = 0; nf < 4; ++nf)
#pragma unroll
          for (int ks = 0; ks < 2; ++ks) bF[nf][ks] = ldB(cur, nf, ks);
      }
      if (pf) {
        if (p < 2) stage_half(nxt, 0, p, Ag, k1);
        else       stage_half(nxt, 1, p - 2, Bg, k1);
      }
      // no leading barrier: other waves' MFMAs cover this wave's reads
      asm volatile("s_waitcnt lgkmcnt(0)" ::: "memory");
      __builtin_amdgcn_sched_barrier(0);
      __builtin_amdgcn_s_setprio(1);
#pragma unroll
      for (int i = 0; i < 2; ++i)
#pragma unroll
        for (int nf = 0; nf < 4; ++nf)
#pragma unroll
          for (int ks = 0; ks < 2; ++ks)
            acc[p * 2 + i][nf] = __builtin_amdgcn_mfma_f32_16x16x32_f16(
                aF[i][ks], bF[nf][ks], acc[p * 2 + i][nf], 0, 0, 0);
      __builtin_amdgcn_s_setprio(0);
      __builtin_amdgcn_sched_barrier(0);
      if (p == 3) asm volatile("s_waitcnt vmcnt(0)" ::: "memory");
      __builtin_amdgcn_s_barrier();
    }
  }

  // ---- epilogue ----
  const int row_l = q4 * 4;
#pragma unroll
  for (int mf = 0; mf < 8; ++mf) {
#pragma unroll
    for (int nf = 0; nf < 4; ++nf) {
      int col = bn * 256 + wn * 64 + nf * 16 + fr;
#pragma unroll
      for (int r4 = 0; r4 < 4; ++r4) {
        int row = bm * 256 + wm * 128 + mf * 16 + row_l + r4;
        if (OUT_F16) {
          ((_Float16*)Cv)[(size_t)row * N + col] = (_Float16)acc[mf][nf][r4];
        } else {
          ((float*)Cv)[(size_t)row * N + col] = acc[mf][nf][r4] + bias[col];
        }
      }
    }
  }
}

// ---------------------------------------------------------------------------
// MFMA attention: one wave per head, 4 heads per block. Rel-table MFMA
// B-frags read directly from precomputed fp16 tables in global (L2-hot).
// All LDS is wave-private -> no __syncthreads at all.
// ---------------------------------------------------------------------------
__global__ __launch_bounds__(256)
void attn_mfma(const _Float16* __restrict__ QKV,
               const _Float16* __restrict__ RKh, const _Float16* __restrict__ RVth,
               _Float16* __restrict__ O) {
  __shared__ _Float16 PB[4][16][72];     // [P(0:16) | zero(16:32) | B2(32:64)]
  __shared__ _Float16 VtP[4][64][40];    // [V^T(0:16) | zero(16:32)]

  const int tid = threadIdx.x;
  const int wave = tid >> 6, lane = tid & 63;

#pragma unroll
  for (int z = 0; z < 6; ++z) {
    int idx = z * 64 + lane;
    int row = idx / 24, cd = idx % 24;
    *(unsigned int*)&PB[wave][row][16 + 2 * cd] = 0u;
  }
#pragma unroll
  for (int z = 0; z < 8; ++z) {
    int idx = z * 64 + lane;
    int row = idx >> 3, cd = idx & 7;
    *(unsigned int*)&VtP[wave][row][16 + 2 * cd] = 0u;
  }

  const int bh = blockIdx.x * 4 + wave;
  const int b = bh >> 4, h = bh & 15;
  const size_t qbase = (size_t)(b * T_SEQ) * 3072 + h * 64;
  const int fr = lane & 15, fk8 = (lane >> 4) * 8;

  half8 aQ0 = *(const half8*)(QKV + qbase + (size_t)fr * 3072 + fk8);
  half8 aQ1 = *(const half8*)(QKV + qbase + (size_t)fr * 3072 + 32 + fk8);
  half8 bK0 = *(const half8*)(QKV + qbase + 1024 + (size_t)fr * 3072 + fk8);
  half8 bK1 = *(const half8*)(QKV + qbase + 1024 + (size_t)fr * 3072 + 32 + fk8);

  half8 rk0a = *(const half8*)(RKh + fr * 64 + fk8);
  half8 rk0b = *(const half8*)(RKh + fr * 64 + 32 + fk8);
  half8 rk1a = *(const half8*)(RKh + (16 + fr) * 64 + fk8);
  half8 rk1b = *(const half8*)(RKh + (16 + fr) * 64 + 32 + fk8);

  {
    const _Float16* vp = QKV + qbase + 2048 + (size_t)fr * 3072 + (lane >> 4) * 16;
    half8 v0 = *(const half8*)vp;
    half8 v1 = *(const half8*)(vp + 8);
    int d0 = (lane >> 4) * 16;
#pragma unroll
    for (int e = 0; e < 8; ++e) VtP[wave][d0 + e][fr] = v0[e];
#pragma unroll
    for (int e = 0; e < 8; ++e) VtP[wave][d0 + 8 + e][fr] = v1[e];
  }

  f32x4 accS = {0.f, 0.f, 0.f, 0.f};
  accS = __builtin_amdgcn_mfma_f32_16x16x32_f16(aQ0, bK0, accS, 0, 0, 0);
  accS = __builtin_amdgcn_mfma_f32_16x16x32_f16(aQ1, bK1, accS, 0, 0, 0);

  f32x4 G0 = {0.f, 0.f, 0.f, 0.f}, G1 = {0.f, 0.f, 0.f, 0.f};
  G0 = __builtin_amdgcn_mfma_f32_16x16x32_f16(aQ0, rk0a, G0, 0, 0, 0);
  G0 = __builtin_amdgcn_mfma_f32_16x16x32_f16(aQ1, rk0b, G0, 0, 0, 0);
  G1 = __builtin_amdgcn_mfma_f32_16x16x32_f16(aQ0, rk1a, G1, 0, 0, 0);
  G1 = __builtin_amdgcn_mfma_f32_16x16x32_f16(aQ1, rk1b, G1, 0, 0, 0);

  const int ibase = (lane >> 4) * 4;
#pragma unroll
  for (int r = 0; r < 4; ++r) {
    const int i = ibase + r;
    const int ridx = fr - i + MAX_REL;
    const int src = (lane & 48) | (ridx & 15);
    float g0 = __shfl(G0[r], src);
    float g1 = __shfl(G1[r], src);
    float g = (ridx >= 16) ? g1 : g0;
    float s = (accS[r] + g) * 0.125f;
    float mx = s;
#pragma unroll
    for (int w = 8; w >= 1; w >>= 1) mx = fmaxf(mx, __shfl_xor(mx, w));
    float e = __expf(s - mx);
    float sum = e;
#pragma unroll
    for (int w = 8; w >= 1; w >>= 1) sum += __shfl_xor(sum, w);
    _Float16 ph = (_Float16)(e / sum);
    PB[wave][i][fr] = ph;
    PB[wave][i][32 + (fr - i + MAX_REL)] = ph;
  }

  half8 aP0 = *(const half8*)&PB[wave][fr][fk8];
  half8 aP1 = *(const half8*)&PB[wave][fr][32 + fk8];
  const size_t obase = (size_t)(b * T_SEQ) * D_MODEL + h * 64;
#pragma unroll
  for (int t = 0; t < 4; ++t) {
    half8 bv = *(const half8*)&VtP[wave][t * 16 + fr][fk8];
    half8 br = *(const half8*)(RVth + (t * 16 + fr) * 32 + fk8);
    f32x4 o = {0.f, 0.f, 0.f, 0.f};
    o = __builtin_amdgcn_mfma_f32_16x16x32_f16(aP0, bv, o, 0, 0, 0);
    o = __builtin_amdgcn_mfma_f32_16x16x32_f16(aP1, br, o, 0, 0, 0);
#pragma unroll
    for (int r = 0; r < 4; ++r)
      O[obase + (size_t)(ibase + r) * D_MODEL + t * 16 + fr] = (_Float16)o[r];
  }
}

// ---------------------------------------------------------------------------
extern "C" void kernel_launch(void* const* d_in, const int* in_sizes, int n_in,
                              void* d_out, int out_size, void* d_ws, size_t ws_size,
                              hipStream_t stream) {
  const float* x  = (const float*)d_in[0];
  const float* Wq = (const float*)d_in[1];
  const float* Wk = (const float*)d_in[2];
  const float* Wv = (const float*)d_in[3];
  const float* Wo = (const float*)d_in[4];
  const float* bo = (const float*)d_in[5];
  const float* rk = (const float*)d_in[6];
  const float* rv = (const float*)d_in[7];
  float* out = (float*)d_out;

  const int total_rows = 2048 * T_SEQ;           // 32768
  const size_t wsz = (size_t)D_MODEL * D_MODEL;  // 1M elems per weight

  _Float16* Wqkvh = (_Float16*)d_ws;             // [Wq;Wk;Wv;Wo] 4M fp16
  _Float16* Woh  = Wqkvh + 3 * wsz;
  _Float16* RKh  = Woh + wsz;            // 32*64 = 2048
  _Float16* RVth = RKh + 2048;           // 64*32 = 2048
  _Float16* chunk_base = RVth + 2048;

  // single prologue launch: all weight conversion + rel tables
  prep_all<<<2049, 256, 0, stream>>>(Wq, Wk, Wv, Wo, Wqkvh, rk, rv, RKh, RVth);

  // per-chunk: xh (1024) + QKV (3072) + AO (1024) fp16 per row
  const size_t per_row_bytes = (size_t)5120 * sizeof(_Float16);
  size_t avail = ws_size - (size_t)(4 * wsz + 4096) * sizeof(_Float16);
  size_t rows_fit = avail / per_row_bytes;
  int rows_c = (rows_fit > (size_t)total_rows) ? total_rows : (int)rows_fit;
  rows_c = (rows_c / 256) * 256;
  if (rows_c < 256) rows_c = 256;

  for (int r0 = 0; r0 < total_rows; r0 += rows_c) {
    int rc = total_rows - r0;
    if (rc > rows_c) rc = rows_c;

    _Float16* xh   = chunk_base;
    _Float16* QKVb = xh + (size_t)rows_c * 1024;
    _Float16* AO   = QKVb + (size_t)rows_c * 3072;

    {
      int n8 = rc * 128;
      cvt_f32_f16<<<(n8 + 255) / 256, 256, 0, stream>>>(
          x + (size_t)r0 * D_MODEL, xh, n8);
    }

    gemm256<true><<<(3072 / 256) * (rc / 256), 512, 0, stream>>>(
        xh, Wqkvh, nullptr, QKVb, rc, 3072, 1024);

    attn_mfma<<<rc / 4, 256, 0, stream>>>(QKVb, RKh, RVth, AO);

    gemm256<false><<<(1024 / 256) * (rc / 256), 512, 0, stream>>>(
        AO, Woh, bo, out + (size_t)r0 * D_MODEL, rc, 1024, 1024);
  }
}

// Round 14
// 402.079 us; speedup vs baseline: 5.8269x; 1.0205x over previous
//
#include <hip/hip_runtime.h>

#define HEADS 16
#define DIM_HEAD 64
#define T_SEQ 16
#define D_MODEL 1024
#define MAX_REL 16

typedef _Float16 half8 __attribute__((ext_vector_type(8)));
typedef float f32x4 __attribute__((ext_vector_type(4)));

// ---------------------------------------------------------------------------
// fp32 -> fp16 conversion, 8 elems/thread (x only)
// ---------------------------------------------------------------------------
__global__ __launch_bounds__(256)
void cvt_f32_f16(const float* __restrict__ in, _Float16* __restrict__ out, int n8) {
  int i = blockIdx.x * blockDim.x + threadIdx.x;
  if (i >= n8) return;
  float4 a = ((const float4*)in)[2 * i];
  float4 b = ((const float4*)in)[2 * i + 1];
  half8 h;
  h[0] = (_Float16)a.x; h[1] = (_Float16)a.y;
  h[2] = (_Float16)a.z; h[3] = (_Float16)a.w;
  h[4] = (_Float16)b.x; h[5] = (_Float16)b.y;
  h[6] = (_Float16)b.z; h[7] = (_Float16)b.w;
  ((half8*)out)[i] = h;
}

// ---------------------------------------------------------------------------
// Single prologue kernel: converts all 4 weights (blocks 0..2047, 512 per
// weight) and preps rel tables (block 2048).
// ---------------------------------------------------------------------------
__global__ __launch_bounds__(256)
void prep_all(const float* __restrict__ Wq, const float* __restrict__ Wk,
              const float* __restrict__ Wv, const float* __restrict__ Wo,
              _Float16* __restrict__ Wdst,
              const float* __restrict__ relk, const float* __restrict__ relv,
              _Float16* __restrict__ RKh, _Float16* __restrict__ RVth) {
  const int bid = blockIdx.x;
  if (bid < 2048) {
    const int w = bid >> 9;  // 0..3
    const float* src = (w == 0) ? Wq : (w == 1) ? Wk : (w == 2) ? Wv : Wo;
    const int local = (bid & 511) * 256 + threadIdx.x;
    float4 a = ((const float4*)src)[2 * local];
    float4 b = ((const float4*)src)[2 * local + 1];
    half8 h;
    h[0] = (_Float16)a.x; h[1] = (_Float16)a.y;
    h[2] = (_Float16)a.z; h[3] = (_Float16)a.w;
    h[4] = (_Float16)b.x; h[5] = (_Float16)b.y;
    h[6] = (_Float16)b.z; h[7] = (_Float16)b.w;
    ((half8*)Wdst)[(size_t)w * 131072 + local] = h;
  } else {
    const int i = threadIdx.x;
    {
      int m = i >> 3, d0 = (i & 7) * 8;
      float4 a = *(const float4*)(relk + m * 64 + d0);
      float4 b = *(const float4*)(relk + m * 64 + d0 + 4);
      half8 h;
      h[0] = (_Float16)a.x; h[1] = (_Float16)a.y;
      h[2] = (_Float16)a.z; h[3] = (_Float16)a.w;
      h[4] = (_Float16)b.x; h[5] = (_Float16)b.y;
      h[6] = (_Float16)b.z; h[7] = (_Float16)b.w;
      *(half8*)(RKh + m * 64 + d0) = h;
    }
    {
      int d = i >> 2, m0 = (i & 3) * 8;
      half8 h;
#pragma unroll
      for (int e = 0; e < 8; ++e) h[e] = (_Float16)relv[(m0 + e) * 64 + d];
      *(half8*)(RVth + d * 32 + m0) = h;
    }
  }
}

// ---------------------------------------------------------------------------
// async global -> LDS, 16B per lane (dest = wave-uniform base + lane*16)
// ---------------------------------------------------------------------------
__device__ __forceinline__ void gload_lds16(const _Float16* g, _Float16* l) {
  __builtin_amdgcn_global_load_lds(
      (const __attribute__((address_space(1))) unsigned int*)(uintptr_t)g,
      (__attribute__((address_space(3))) unsigned int*)(uintptr_t)l, 16, 0, 0);
}

// ---------------------------------------------------------------------------
// 256x256 MFMA fp16 GEMM, BK=64, 8 waves (2M x 4N), 2-phase pipeline.
// C[M,N] = A[M,K]*B[N,K]^T. LDS [buf][A/B][half][128][64] fp16 = 128 KB,
// XOR-swizzled 16B slots (slot ^= row&7), staged via global_load_lds with
// pre-swizzled global source. R8-proven fences kept; phases merged 4 -> 2:
//   p0: read B + A q0,q1 | stage A-halves t+1 | lgkm0+SB | 32 MFMA | bar
//   p1: read A q2,q3     | stage B-halves t+1 | lgkm0+SB | 32 MFMA |
//       vmcnt(0) | bar
// Halves barrier/fence overhead per tile; MFMA region doubles (more cover).
// ---------------------------------------------------------------------------
template <bool OUT_F16>
__global__ __launch_bounds__(512, 2)
void gemm256(const _Float16* __restrict__ A, const _Float16* __restrict__ B,
             const float* __restrict__ bias, void* __restrict__ Cv,
             int M, int N, int K) {
  __shared__ _Float16 lds[2][2][2][128][64];
  const int tid = threadIdx.x;
  const int wave = tid >> 6, lane = tid & 63;
  const int wm = wave >> 2, wn = wave & 3;

  // XCD-aware bijective remap (m204)
  const int GN = N >> 8;
  const int nwg = gridDim.x;
  const int q = nwg >> 3, r = nwg & 7;
  const int xcd = blockIdx.x & 7, pos = blockIdx.x >> 3;
  const int wgid = (xcd < r ? xcd * (q + 1) : r * (q + 1) + (xcd - r) * q) + pos;
  const int bm = wgid / GN, bn = wgid % GN;

  const int fr = lane & 15;          // frag row/col within 16
  const int q4 = lane >> 4;          // 0..3 : 16B slot within 64B k-half
  const int l3 = lane >> 3;          // staging row within 8-row group
  const int sl = (lane & 7) ^ l3;    // pre-swizzled source slot

  const _Float16* Ag = A + (size_t)(bm * 256) * K;
  const _Float16* Bg = B + (size_t)(bn * 256) * K;

  f32x4 acc[8][4];
#pragma unroll
  for (int m = 0; m < 8; ++m)
#pragma unroll
    for (int n = 0; n < 4; ++n) acc[m][n] = (f32x4){0.f, 0.f, 0.f, 0.f};

  // stage one 128x64 half-tile (2 x gload_lds per thread)
  auto stage_half = [&](int buf, int ab, int half, const _Float16* G, int k0) {
#pragma unroll
    for (int i = 0; i < 2; ++i) {
      int g = wave * 2 + i;  // 8-row group 0..15
      const _Float16* src =
          G + (size_t)(half * 128 + g * 8 + l3) * K + k0 + sl * 8;
      gload_lds16(src, &lds[buf][ab][half][g * 8][0]);
    }
  };

  auto ldA = [&](int buf, int mf, int ks) {
    unsigned off = (unsigned)((mf * 16 + fr) * 128 + (ks * 4 + q4) * 16) ^
                   (unsigned)((fr & 7) << 4);
    return *(const half8*)((const char*)&lds[buf][0][wm][0][0] + off);
  };
  auto ldB = [&](int buf, int nf, int ks) {
    int rowB = wn * 64 + nf * 16 + fr;
    unsigned off = (unsigned)((rowB & 127) * 128 + (ks * 4 + q4) * 16) ^
                   (unsigned)((fr & 7) << 4);
    return *(const half8*)((const char*)&lds[buf][1][rowB >> 7][0][0] + off);
  };

  // prologue: stage tile 0 fully
#pragma unroll
  for (int h = 0; h < 2; ++h) {
    stage_half(0, 0, h, Ag, 0);
    stage_half(0, 1, h, Bg, 0);
  }
  asm volatile("s_waitcnt vmcnt(0)" ::: "memory");
  __builtin_amdgcn_s_barrier();

  const int NT = K >> 6;
  for (int t = 0; t < NT; ++t) {
    const int cur = t & 1, nxt = cur ^ 1;
    const bool pf = (t + 1 < NT);
    const int k1 = (t + 1) << 6;
    half8 bF[4][2], aF[4][2];

    // ---- p0: read B + A q0,q1; stage A-halves of t+1 ----
#pragma unroll
    for (int nf = 0; nf < 4; ++nf)
#pragma unroll
      for (int ks = 0; ks < 2; ++ks) bF[nf][ks] = ldB(cur, nf, ks);
#pragma unroll
    for (int i = 0; i < 4; ++i)
#pragma unroll
      for (int ks = 0; ks < 2; ++ks) aF[i][ks] = ldA(cur, i, ks);
    if (pf) {
      stage_half(nxt, 0, 0, Ag, k1);
      stage_half(nxt, 0, 1, Ag, k1);
    }
    asm volatile("s_waitcnt lgkmcnt(0)" ::: "memory");
    __builtin_amdgcn_sched_barrier(0);
    __builtin_amdgcn_s_setprio(1);
#pragma unroll
    for (int i = 0; i < 4; ++i)
#pragma unroll
      for (int nf = 0; nf < 4; ++nf)
#pragma unroll
        for (int ks = 0; ks < 2; ++ks)
          acc[i][nf] = __builtin_amdgcn_mfma_f32_16x16x32_f16(
              aF[i][ks], bF[nf][ks], acc[i][nf], 0, 0, 0);
    __builtin_amdgcn_s_setprio(0);
    __builtin_amdgcn_sched_barrier(0);
    __builtin_amdgcn_s_barrier();

    // ---- p1: read A q2,q3; stage B-halves of t+1; tile-end drain ----
#pragma unroll
    for (int i = 0; i < 4; ++i)
#pragma unroll
      for (int ks = 0; ks < 2; ++ks) aF[i][ks] = ldA(cur, 4 + i, ks);
    if (pf) {
      stage_half(nxt, 1, 0, Bg, k1);
      stage_half(nxt, 1, 1, Bg, k1);
    }
    asm volatile("s_waitcnt lgkmcnt(0)" ::: "memory");
    __builtin_amdgcn_sched_barrier(0);
    __builtin_amdgcn_s_setprio(1);
#pragma unroll
    for (int i = 0; i < 4; ++i)
#pragma unroll
      for (int nf = 0; nf < 4; ++nf)
#pragma unroll
        for (int ks = 0; ks < 2; ++ks)
          acc[4 + i][nf] = __builtin_amdgcn_mfma_f32_16x16x32_f16(
              aF[i][ks], bF[nf][ks], acc[4 + i][nf], 0, 0, 0);
    __builtin_amdgcn_s_setprio(0);
    __builtin_amdgcn_sched_barrier(0);
    if (pf) asm volatile("s_waitcnt vmcnt(0)" ::: "memory");
    __builtin_amdgcn_s_barrier();
  }

  // ---- epilogue ----
  const int row_l = q4 * 4;
#pragma unroll
  for (int mf = 0; mf < 8; ++mf) {
#pragma unroll
    for (int nf = 0; nf < 4; ++nf) {
      int col = bn * 256 + wn * 64 + nf * 16 + fr;
#pragma unroll
      for (int r4 = 0; r4 < 4; ++r4) {
        int row = bm * 256 + wm * 128 + mf * 16 + row_l + r4;
        if (OUT_F16) {
          ((_Float16*)Cv)[(size_t)row * N + col] = (_Float16)acc[mf][nf][r4];
        } else {
          ((float*)Cv)[(size_t)row * N + col] = acc[mf][nf][r4] + bias[col];
        }
      }
    }
  }
}

// ---------------------------------------------------------------------------
// MFMA attention: one wave per head, 4 heads per block. Rel-table MFMA
// B-frags read directly from precomputed fp16 tables in global (L2-hot).
// All LDS is wave-private -> no __syncthreads at all.
// ---------------------------------------------------------------------------
__global__ __launch_bounds__(256)
void attn_mfma(const _Float16* __restrict__ QKV,
               const _Float16* __restrict__ RKh, const _Float16* __restrict__ RVth,
               _Float16* __restrict__ O) {
  __shared__ _Float16 PB[4][16][72];     // [P(0:16) | zero(16:32) | B2(32:64)]
  __shared__ _Float16 VtP[4][64][40];    // [V^T(0:16) | zero(16:32)]

  const int tid = threadIdx.x;
  const int wave = tid >> 6, lane = tid & 63;

#pragma unroll
  for (int z = 0; z < 6; ++z) {
    int idx = z * 64 + lane;
    int row = idx / 24, cd = idx % 24;
    *(unsigned int*)&PB[wave][row][16 + 2 * cd] = 0u;
  }
#pragma unroll
  for (int z = 0; z < 8; ++z) {
    int idx = z * 64 + lane;
    int row = idx >> 3, cd = idx & 7;
    *(unsigned int*)&VtP[wave][row][16 + 2 * cd] = 0u;
  }

  const int bh = blockIdx.x * 4 + wave;
  const int b = bh >> 4, h = bh & 15;
  const size_t qbase = (size_t)(b * T_SEQ) * 3072 + h * 64;
  const int fr = lane & 15, fk8 = (lane >> 4) * 8;

  half8 aQ0 = *(const half8*)(QKV + qbase + (size_t)fr * 3072 + fk8);
  half8 aQ1 = *(const half8*)(QKV + qbase + (size_t)fr * 3072 + 32 + fk8);
  half8 bK0 = *(const half8*)(QKV + qbase + 1024 + (size_t)fr * 3072 + fk8);
  half8 bK1 = *(const half8*)(QKV + qbase + 1024 + (size_t)fr * 3072 + 32 + fk8);

  half8 rk0a = *(const half8*)(RKh + fr * 64 + fk8);
  half8 rk0b = *(const half8*)(RKh + fr * 64 + 32 + fk8);
  half8 rk1a = *(const half8*)(RKh + (16 + fr) * 64 + fk8);
  half8 rk1b = *(const half8*)(RKh + (16 + fr) * 64 + 32 + fk8);

  {
    const _Float16* vp = QKV + qbase + 2048 + (size_t)fr * 3072 + (lane >> 4) * 16;
    half8 v0 = *(const half8*)vp;
    half8 v1 = *(const half8*)(vp + 8);
    int d0 = (lane >> 4) * 16;
#pragma unroll
    for (int e = 0; e < 8; ++e) VtP[wave][d0 + e][fr] = v0[e];
#pragma unroll
    for (int e = 0; e < 8; ++e) VtP[wave][d0 + 8 + e][fr] = v1[e];
  }

  f32x4 accS = {0.f, 0.f, 0.f, 0.f};
  accS = __builtin_amdgcn_mfma_f32_16x16x32_f16(aQ0, bK0, accS, 0, 0, 0);
  accS = __builtin_amdgcn_mfma_f32_16x16x32_f16(aQ1, bK1, accS, 0, 0, 0);

  f32x4 G0 = {0.f, 0.f, 0.f, 0.f}, G1 = {0.f, 0.f, 0.f, 0.f};
  G0 = __builtin_amdgcn_mfma_f32_16x16x32_f16(aQ0, rk0a, G0, 0, 0, 0);
  G0 = __builtin_amdgcn_mfma_f32_16x16x32_f16(aQ1, rk0b, G0, 0, 0, 0);
  G1 = __builtin_amdgcn_mfma_f32_16x16x32_f16(aQ0, rk1a, G1, 0, 0, 0);
  G1 = __builtin_amdgcn_mfma_f32_16x16x32_f16(aQ1, rk1b, G1, 0, 0, 0);

  const int ibase = (lane >> 4) * 4;
#pragma unroll
  for (int r = 0; r < 4; ++r) {
    const int i = ibase + r;
    const int ridx = fr - i + MAX_REL;
    const int src = (lane & 48) | (ridx & 15);
    float g0 = __shfl(G0[r], src);
    float g1 = __shfl(G1[r], src);
    float g = (ridx >= 16) ? g1 : g0;
    float s = (accS[r] + g) * 0.125f;
    float mx = s;
#pragma unroll
    for (int w = 8; w >= 1; w >>= 1) mx = fmaxf(mx, __shfl_xor(mx, w));
    float e = __expf(s - mx);
    float sum = e;
#pragma unroll
    for (int w = 8; w >= 1; w >>= 1) sum += __shfl_xor(sum, w);
    _Float16 ph = (_Float16)(e / sum);
    PB[wave][i][fr] = ph;
    PB[wave][i][32 + (fr - i + MAX_REL)] = ph;
  }

  half8 aP0 = *(const half8*)&PB[wave][fr][fk8];
  half8 aP1 = *(const half8*)&PB[wave][fr][32 + fk8];
  const size_t obase = (size_t)(b * T_SEQ) * D_MODEL + h * 64;
#pragma unroll
  for (int t = 0; t < 4; ++t) {
    half8 bv = *(const half8*)&VtP[wave][t * 16 + fr][fk8];
    half8 br = *(const half8*)(RVth + (t * 16 + fr) * 32 + fk8);
    f32x4 o = {0.f, 0.f, 0.f, 0.f};
    o = __builtin_amdgcn_mfma_f32_16x16x32_f16(aP0, bv, o, 0, 0, 0);
    o = __builtin_amdgcn_mfma_f32_16x16x32_f16(aP1, br, o, 0, 0, 0);
#pragma unroll
    for (int r = 0; r < 4; ++r)
      O[obase + (size_t)(ibase + r) * D_MODEL + t * 16 + fr] = (_Float16)o[r];
  }
}

// ---------------------------------------------------------------------------
extern "C" void kernel_launch(void* const* d_in, const int* in_sizes, int n_in,
                              void* d_out, int out_size, void* d_ws, size_t ws_size,
                              hipStream_t stream) {
  const float* x  = (const float*)d_in[0];
  const float* Wq = (const float*)d_in[1];
  const float* Wk = (const float*)d_in[2];
  const float* Wv = (const float*)d_in[3];
  const float* Wo = (const float*)d_in[4];
  const float* bo = (const float*)d_in[5];
  const float* rk = (const float*)d_in[6];
  const float* rv = (const float*)d_in[7];
  float* out = (float*)d_out;

  const int total_rows = 2048 * T_SEQ;           // 32768
  const size_t wsz = (size_t)D_MODEL * D_MODEL;  // 1M elems per weight

  _Float16* Wqkvh = (_Float16*)d_ws;             // [Wq;Wk;Wv;Wo] 4M fp16
  _Float16* Woh  = Wqkvh + 3 * wsz;
  _Float16* RKh  = Woh + wsz;            // 32*64 = 2048
  _Float16* RVth = RKh + 2048;           // 64*32 = 2048
  _Float16* chunk_base = RVth + 2048;

  // single prologue launch: all weight conversion + rel tables
  prep_all<<<2049, 256, 0, stream>>>(Wq, Wk, Wv, Wo, Wqkvh, rk, rv, RKh, RVth);

  // per-chunk: xh (1024) + QKV (3072) + AO (1024) fp16 per row
  const size_t per_row_bytes = (size_t)5120 * sizeof(_Float16);
  size_t avail = ws_size - (size_t)(4 * wsz + 4096) * sizeof(_Float16);
  size_t rows_fit = avail / per_row_bytes;
  int rows_c = (rows_fit > (size_t)total_rows) ? total_rows : (int)rows_fit;
  rows_c = (rows_c / 256) * 256;
  if (rows_c < 256) rows_c = 256;

  for (int r0 = 0; r0 < total_rows; r0 += rows_c) {
    int rc = total_rows - r0;
    if (rc > rows_c) rc = rows_c;

    _Float16* xh   = chunk_base;
    _Float16* QKVb = xh + (size_t)rows_c * 1024;
    _Float16* AO   = QKVb + (size_t)rows_c * 3072;

    {
      int n8 = rc * 128;
      cvt_f32_f16<<<(n8 + 255) / 256, 256, 0, stream>>>(
          x + (size_t)r0 * D_MODEL, xh, n8);
    }

    gemm256<true><<<(3072 / 256) * (rc / 256), 512, 0, stream>>>(
        xh, Wqkvh, nullptr, QKVb, rc, 3072, 1024);

    attn_mfma<<<rc / 4, 256, 0, stream>>>(QKVb, RKh, RVth, AO);

    gemm256<false><<<(1024 / 256) * (rc / 256), 512, 0, stream>>>(
        AO, Woh, bo, out + (size_t)r0 * D_MODEL, rc, 1024, 1024);
  }
}